// Round 19
// baseline (92.722 us; speedup 1.0000x reference)
//
#include <hip/hip_runtime.h>
#include <hip/hip_bf16.h>

// ECC / edge-conditioned aggregation, fused single kernel:
//   A = relu(edges @ W^T + bias)   [B,N*N,D*D] (bf16 MFMA, f32 accum)
//   out[b,i,:] = sum_j mask[b,ij] * (A[b,ij,:,:] @ nodes[b,j,:])
//
// Grid = B*N blocks (one per (b,i)), 256 threads = 4 waves. MFMA M=g, N=j,
// K=f; each 16x16 C-tile is one dout (dout = wv*8+g8; e = par*16+grp*4+reg).
//
// R19 (from R18 counters + inspection):
//  - FULL W bf16 in LDS (64 KB), staged once. Total LDS 76.6 KB -> 2
//    blocks/CU -> the allocator's occupancy-driven VGPR cap relaxes to
//    >=128 -> no spill (R2..R17: small-LDS kernels got capped at 64 and
//    spilled 75-127 MB of scratch; attributes couldn't raise the cap, R11).
//  - XOR-swizzle wlds (granule ^= row&3): the linear layout was an 8-way
//    bank conflict on every afrag ds_read_b128 (64B row stride, G4 trap).
//  - Mask compaction: mask is exactly 0/1; wave 0 ballots the 64-bit mask
//    row, builds jlist of active j's. j-tiles drop 4 -> ceil(cnt/16)
//    (E~2.5). Pad slots read exact-zero nmask rows -> contribution 0.
//    Skipped terms were exactly 0 (relu(..)*0), so the sum is unchanged.
//  - Single kernel, no d_ws (R15: harness ws re-poison races chained use).

#define B_ 16
#define N_ 64
#define D_ 32
#define F_ 32
#define NP 33  // nmask row stride (pad +1)

typedef __attribute__((ext_vector_type(8))) short bf16x8;
typedef __attribute__((ext_vector_type(4))) float f32x4;

__device__ __forceinline__ short f2bf(float x) {
    // round-to-nearest-even f32 -> bf16 (proven R2/R11/R17/R18: absmax 0.25)
    unsigned u = __builtin_bit_cast(unsigned, x);
    u += 0x7fffu + ((u >> 16) & 1u);
    return (short)(u >> 16);
}

__global__ __launch_bounds__(256) void ecc_fused_kernel(
    const float* __restrict__ nodes,  // [16][64][32]
    const float* __restrict__ edges,  // [16][4096][32]
    const float* __restrict__ mask,   // [16][4096]
    const float* __restrict__ W,      // [1024][32]
    const float* __restrict__ bias,   // [1024]
    float* __restrict__ out)          // [16][64][32]
{
    __shared__ short wlds[D_ * D_ * F_];  // 64 KB: full W as bf16, swizzled
    __shared__ float nmask[N_ * NP];      // 8448 B: compacted nodes (0-padded)
    __shared__ float blds[D_ * D_];       // 4 KB: bias
    __shared__ int   jlist[N_];           // compacted active-j indices
    __shared__ int   jcnt;

    const int tid  = threadIdx.x;
    const int lane = tid & 63;
    const int wv   = tid >> 6;   // wave 0..3
    const int col  = lane & 15;  // MFMA 16-index: A-row(g) / B-col(j) / C-col(j)
    const int grp  = lane >> 4;  // 0..3: K-block for A/B, row-group for C
    const int bi   = blockIdx.x; // 0..1023
    const int b    = bi >> 6;
    const int i    = bi & 63;
    const int f0   = grp * 8;    // K offset this lane covers in A/B operands

    // ---- Phase A: stage bias + full W (f32->bf16, swizzled); wave0 compacts mask
    *(f32x4*)(blds + tid * 4) = *(const f32x4*)(bias + tid * 4);

    if (tid < 64) {  // wave 0: ballot-compact the mask row (mask is 0/1)
        const float mk = mask[b * (N_ * N_) + i * N_ + tid];
        jlist[tid] = 0;                       // default (pad-safe, ordered in-wave)
        const unsigned long long act = __ballot(mk != 0.0f);
        if (tid == 0) jcnt = (int)__popcll(act);
        if (mk != 0.0f) {
            const int pos = (int)__popcll(act & ((1ull << tid) - 1ull));
            jlist[pos] = tid;
        }
    }

#pragma unroll 1
    for (int k = 0; k < 16; ++k) {            // 16*256*8 = 32768 elems
        const int lidx = k * 2048 + tid * 8;  // granule-aligned (8 shorts)
        const int lr   = lidx >> 5;           // W row 0..1023
        const int fo   = lidx & 31;           // 0,8,16,24
        const float* s = W + lr * F_ + fo;
        f32x4 a0 = *(const f32x4*)s;
        f32x4 a1 = *(const f32x4*)(s + 4);
        bf16x8 t;
        t[0] = f2bf(a0[0]); t[1] = f2bf(a0[1]);
        t[2] = f2bf(a0[2]); t[3] = f2bf(a0[3]);
        t[4] = f2bf(a1[0]); t[5] = f2bf(a1[1]);
        t[6] = f2bf(a1[2]); t[7] = f2bf(a1[3]);
        // swizzle: 16B granule index ^= (row & 3)  -> 2-way max on reads
        *(bf16x8*)(wlds + lr * F_ + (fo ^ ((lr & 3) * 8))) = t;
    }
    __syncthreads();

    // ---- Phase B: stage compacted nmask (slot-indexed; pads = exact 0)
    {
        const int slot = tid >> 2;            // 0..63
        const int c0   = (tid & 3) * 8;       // 0,8,16,24
        f32x4 v0 = {0.f, 0.f, 0.f, 0.f}, v1 = {0.f, 0.f, 0.f, 0.f};
        if (slot < jcnt) {                    // active slots have mask==1 exactly
            const float* np = nodes + (b * N_ + jlist[slot]) * D_ + c0;
            v0 = *(const f32x4*)np;
            v1 = *(const f32x4*)(np + 4);
        }
        float* dst = &nmask[slot * NP + c0];
        dst[0] = v0[0]; dst[1] = v0[1]; dst[2] = v0[2]; dst[3] = v0[3];
        dst[4] = v1[0]; dst[5] = v1[1]; dst[6] = v1[2]; dst[7] = v1[3];
    }

    const int NT = (jcnt + 15) >> 4;          // active j-tiles: 0..4 (uniform)

    // ---- Edge B-fragments for compacted columns (converted once)
    const float* eb = edges + (b * (N_ * N_) + i * N_) * F_;
    bf16x8 bfrag[4];
#pragma unroll
    for (int jt = 0; jt < 4; ++jt) {
        if (jt < NT) {
            const int j = jlist[jt * 16 + col];   // slot's source j (pads -> 0, valid)
            const float* s = eb + j * F_ + f0;
            f32x4 e0 = *(const f32x4*)s;
            f32x4 e1 = *(const f32x4*)(s + 4);
            bf16x8 t;
            t[0] = f2bf(e0[0]); t[1] = f2bf(e0[1]);
            t[2] = f2bf(e0[2]); t[3] = f2bf(e0[3]);
            t[4] = f2bf(e1[0]); t[5] = f2bf(e1[1]);
            t[6] = f2bf(e1[2]); t[7] = f2bf(e1[3]);
            bfrag[jt] = t;
        }
    }
    __syncthreads();

    float acc[8] = {0.f, 0.f, 0.f, 0.f, 0.f, 0.f, 0.f, 0.f};

    // g = gt*16 + grp*4 + reg, gt = wv*16 + g8*2 + par;
    // dout = wv*8 + g8 ; e = par*16 + grp*4 + reg.
#pragma unroll 1
    for (int par = 0; par < 2; ++par) {
        // node slice for this e-half: 16 regs, reused across 8 g-tiles
        float nd[4][4];
#pragma unroll
        for (int jt = 0; jt < 4; ++jt) {
            if (jt < NT) {
                const float* n = &nmask[(jt * 16 + col) * NP + par * 16 + grp * 4];
                nd[jt][0] = n[0]; nd[jt][1] = n[1];
                nd[jt][2] = n[2]; nd[jt][3] = n[3];
            }
        }

#pragma unroll 1
        for (int g8 = 0; g8 < 8; ++g8) {      // static acc index (rule #20)
            const int gt  = wv * 16 + g8 * 2 + par;
            const int row = gt * 16 + col;    // W row this lane supplies
            // swizzled A-fragment read: granule grp ^ (row&3) -> <=2-way banks
            bf16x8 afrag = *(const bf16x8*)(wlds + row * F_ + ((grp ^ (row & 3)) * 8));
            // bias C-in: bias[g], g = gt*16 + grp*4 + reg (16B-aligned, broadcast)
            f32x4 bfr = *(const f32x4*)(blds + gt * 16 + grp * 4);

#pragma unroll
            for (int jt = 0; jt < 4; ++jt) {
                if (jt < NT) {
                    f32x4 c = __builtin_amdgcn_mfma_f32_16x16x32_bf16(afrag, bfrag[jt], bfr, 0, 0, 0);
                    float s = fmaxf(c[0], 0.f) * nd[jt][0];
                    s += fmaxf(c[1], 0.f) * nd[jt][1];
                    s += fmaxf(c[2], 0.f) * nd[jt][2];
                    s += fmaxf(c[3], 0.f) * nd[jt][3];
                    acc[g8] += s;   // dout = wv*8 + g8 (both par halves accumulate)
                }
            }
        }
    }

    // ---- Full-wave reduction: sum over 16 j-columns x 4 e-groups (64 lanes)
#pragma unroll
    for (int dl = 0; dl < 8; ++dl) {
        float v = acc[dl];
#pragma unroll
        for (int off = 32; off > 0; off >>= 1) v += __shfl_xor(v, off, 64);
        acc[dl] = v;
    }

    if (lane == 0) {
        float* op = out + (b * N_ + i) * D_ + wv * 8;
#pragma unroll
        for (int dl = 0; dl < 8; ++dl) op[dl] = acc[dl];
    }
}

extern "C" void kernel_launch(void* const* d_in, const int* in_sizes, int n_in,
                              void* d_out, int out_size, void* d_ws, size_t ws_size,
                              hipStream_t stream) {
    const float* nodes = (const float*)d_in[0];  // 16*64*32
    const float* edges = (const float*)d_in[1];  // 16*4096*32
    const float* mask  = (const float*)d_in[2];  // 16*4096
    const float* W     = (const float*)d_in[3];  // 1024*32
    const float* bias  = (const float*)d_in[4];  // 1024
    float* outp        = (float*)d_out;          // 16*64*32

    ecc_fused_kernel<<<dim3(B_ * N_), dim3(256), 0, stream>>>(
        nodes, edges, mask, W, bias, outp);
}